// Round 1
// baseline (102.130 us; speedup 1.0000x reference)
//
#include <hip/hip_runtime.h>

// Problem constants (match reference): B=8192, P=32, D=128, V=100000
#define BB 8192
#define PP 32
#define DD 128
#define HP 16   // pairs handled per wave (half a row)

// Split-row gather: TWO waves per batch row, each owning 16 contiguous
// path positions. Rationale: the previous exact-fit launch (8192 waves on
// 8192 resident slots, one row/wave) was tail-bound — per-SIMD time is the
// max of 8 uniform[1,31] path lengths (~30) vs mean work 16. Splitting
// halves the variance (per-wave work <= 16) and makes the grid 2x
// oversubscribed (16384 waves), so retired slots refill and imbalance
// averages out. Wave hh=1 exits immediately for rows with len<=16 (half
// of them), but MUST still write its zero partial (workspace is poisoned).
//
// Per-pair 512B embed row is still loaded by a full 32-lane half-wave as
// one float4/lane instruction -> 8 distinct 64B lines per pair (minimum).
// Halves interleave pairs (pid = p0 + 2j + h) to keep exec masks full.
//
// Reduction: lane writes its 4-elem partial to a wave-private stride-33
// LDS slice (banks: distinct within a half, 2-way across halves = free).
// Phase 2 uses 4 lanes per pair (8 reads each) + 2-step shfl_xor(16,32)
// butterfly. No __syncthreads anywhere.
__global__ __launch_bounds__(256) void hs_loss_kernel(
    const float* __restrict__ hidden,      // [B, D]
    const int*   __restrict__ path,        // [B, P]
    const int*   __restrict__ path_len,    // [B]
    const int*   __restrict__ code,        // [B, P]
    const float* __restrict__ embed,       // [V, D]
    float2* __restrict__ partials)         // [2*BB] {loss_sum, count} per half-row
{
    const int tid = threadIdx.x;
    const int w   = tid >> 6;              // wave in block, 0..3
    const int l   = tid & 63;              // lane
    const int h   = l >> 5;                // half, 0 or 1
    const int hl  = l & 31;                // lane within half
    const int gw  = blockIdx.x * 4 + w;    // global wave id
    const int b   = gw >> 1;               // batch row
    const int s   = (gw & 1) << 4;         // path offset: 0 or 16

    __shared__ float plds[4][HP * 33];     // 4 wave-private slices, 8.4 KB
    float* const myp = plds[w];

    const int len     = path_len[b];               // wave-uniform
    const int len_loc = min(max(len - s, 0), HP);  // this wave's valid pairs

    if (len_loc == 0) {                    // wave-uniform early exit
        if (l == 0) partials[gw] = make_float2(0.0f, 0.0f);
        return;
    }

    const int idx_l = path[b * PP + hl];   // lane hl holds pair hl's index
    const int cd_l  = code[b * PP + hl];   // (both halves duplicate)

    // lane's 16B slice of the hidden row (both halves identical -> L1 hit)
    const float4 hv = ((const float4*)(hidden + (size_t)b * DD))[hl];

    // ---- phase 1: batched full-row loads + partial dots ----
    #pragma unroll
    for (int batch = 0; batch < 2; ++batch) {
        const int p0 = batch * 8;          // local pids p0..p0+7
        if (p0 < len_loc) {                // wave-uniform batch skip
            int pl[4];
            float4 e[4];
            #pragma unroll
            for (int j = 0; j < 4; ++j) {
                pl[j] = p0 + 2 * j + h;    // halves interleave pairs
                const int idx = __shfl(idx_l, s + pl[j]);
                if (pl[j] < len_loc)       // half-uniform exec mask
                    e[j] = ((const float4*)(embed + (size_t)idx * DD))[hl];
            }
            #pragma unroll
            for (int j = 0; j < 4; ++j) {
                if (pl[j] < len_loc) {
                    const float pr = e[j].x * hv.x + e[j].y * hv.y
                                   + e[j].z * hv.z + e[j].w * hv.w;
                    myp[pl[j] * 33 + hl] = pr;
                }
            }
        }
    }

    // ---- phase 2: 4 lanes per pair (no barrier: same-wave LDS) ----
    const int lp = l & 15;                 // local pair this lane reduces
    const int kb = (l >> 4) * 8;           // quarter of the 32 partials
    float psum = 0.0f;
    #pragma unroll
    for (int k = 0; k < 8; ++k) psum += myp[lp * 33 + kb + k];
    float dot = psum + __shfl_xor(psum, 16);
    dot += __shfl_xor(dot, 32);            // all lanes hold dot of pair lp

    // code bit for this lane's pair (shfl with full wave active)
    const int cd = __shfl(cd_l, s + lp);

    // ---- phase 3: softplus + 16-lane reduction ----
    float loss = 0.0f;
    if (l < 16 && lp < len_loc) {
        // loss = softplus(code ? -dot : dot), stable BCE form
        const float z = cd ? -dot : dot;
        loss = fmaxf(z, 0.0f) + __logf(1.0f + __expf(-fabsf(z)));
    }
    #pragma unroll
    for (int m = 1; m <= 8; m <<= 1) loss += __shfl_xor(loss, m);
    if (l == 0) partials[gw] = make_float2(loss, (float)len_loc);
}

// Single-block reduction of the 16384 per-half-row partials + final divide.
__global__ __launch_bounds__(1024) void hs_finalize_kernel(
    const float2* __restrict__ partials, float* __restrict__ out)
{
    const int tid = threadIdx.x;
    float ls = 0.0f, cs = 0.0f;
    #pragma unroll
    for (int k = 0; k < (2 * BB) / 1024; ++k) {
        const float2 v = partials[tid + k * 1024];
        ls += v.x;
        cs += v.y;
    }
    #pragma unroll
    for (int m = 1; m <= 32; m <<= 1) {
        ls += __shfl_xor(ls, m);
        cs += __shfl_xor(cs, m);
    }
    __shared__ float s_l[16], s_c[16];
    const int wave = tid >> 6;
    if ((tid & 63) == 0) { s_l[wave] = ls; s_c[wave] = cs; }
    __syncthreads();
    if (tid == 0) {
        float L = 0.0f, C = 0.0f;
        #pragma unroll
        for (int wv = 0; wv < 16; ++wv) { L += s_l[wv]; C += s_c[wv]; }
        out[0] = L / C;
    }
}

extern "C" void kernel_launch(void* const* d_in, const int* in_sizes, int n_in,
                              void* d_out, int out_size, void* d_ws, size_t ws_size,
                              hipStream_t stream) {
    const float* hidden   = (const float*)d_in[0];  // [B, D] f32
    // d_in[1] = target (unused by the reference computation)
    const int*   path     = (const int*)d_in[2];    // [B, P]
    const int*   path_len = (const int*)d_in[3];    // [B]
    const int*   code     = (const int*)d_in[4];    // [B, P]
    const float* embed    = (const float*)d_in[5];  // [V, D] f32
    float*  out      = (float*)d_out;
    float2* partials = (float2*)d_ws;               // 16384 * 8B = 128 KB

    hs_loss_kernel<<<(2 * BB) / 4, 256, 0, stream>>>(hidden, path, path_len,
                                                     code, embed, partials);
    hs_finalize_kernel<<<1, 1024, 0, stream>>>(partials, out);
}

// Round 2
// 100.927 us; speedup vs baseline: 1.0119x; 1.0119x over previous
//
#include <hip/hip_runtime.h>

// Problem constants (match reference): B=8192, P=32, D=128, V=100000
#define BB 8192
#define PP 32
#define DD 128

// One wave per batch row (verified-best mapping); block = 4 waves;
// grid = 2048 (8 blocks/CU, exact-fit: 16.5 KB LDS, <=64 VGPR -> 32
// waves/CU). Each pair's 512B embed row is loaded by a full 32-lane
// HALF-WAVE as one float4/lane instruction -> 8 distinct 64B lines per
// pair (minimum line-lookups, ~1.1M total). Halves process interleaved
// pairs pid = 2j+h so exec masks stay near-full for any len.
//
// MLP: 4 pair-loads batched into registers before any consumption
// (e[4] = 16 VGPRs keeps total <=64 -> 8 waves/SIMD).
//
// Reduction: lane writes its 4-elem partial to a wave-private stride-33
// LDS slice (writes: banks distinct per half, 2-way across halves = free;
// reads: bank bijection, 2-way = free). Lane l sums half the 32 partials
// of pair (l&31), combines with shfl_xor(32), softplus, wave-reduce.
// NEW vs round-0: block-level pre-reduction (one __syncthreads, free at
// block-granularity retirement) -> finalize reads 2048 not 8192 partials.
__global__ __launch_bounds__(256) void hs_loss_kernel(
    const float* __restrict__ hidden,      // [B, D]
    const int*   __restrict__ path,        // [B, P]
    const int*   __restrict__ path_len,    // [B]
    const int*   __restrict__ code,        // [B, P]
    const float* __restrict__ embed,       // [V, D]
    float2* __restrict__ partials)         // [2048] {loss_sum, count} per block
{
    const int tid = threadIdx.x;
    const int w   = tid >> 6;              // wave in block, 0..3
    const int l   = tid & 63;              // lane
    const int h   = l >> 5;                // half, 0 or 1
    const int hl  = l & 31;                // lane within half
    const int b   = blockIdx.x * 4 + w;    // this wave's batch row

    __shared__ float plds[4][PP * 33];     // 4 wave-private slices, 16.5 KB
    __shared__ float2 bpart[4];
    float* const myp = plds[w];

    const int len   = path_len[b];         // wave-uniform
    const int idx_l = path[b * PP + hl];   // lane hl holds pair hl's index
    const int cd_l  = code[b * PP + hl];   // (both halves duplicate)

    // lane's 16B slice of the hidden row (both halves identical -> L1 hit)
    const float4 hv = ((const float4*)(hidden + (size_t)b * DD))[hl];

    // ---- phase 1: batched full-row loads + partial dots ----
    #pragma unroll
    for (int batch = 0; batch < 4; ++batch) {
        const int p0 = batch * 8;          // this batch covers pids p0..p0+7
        if (p0 < len) {                    // wave-uniform batch skip
            int pid[4];
            float4 e[4];
            #pragma unroll
            for (int j = 0; j < 4; ++j) {
                pid[j] = p0 + 2 * j + h;   // halves interleave pairs
                const int idx = __shfl(idx_l, pid[j]);
                if (pid[j] < len)          // half-uniform exec mask
                    e[j] = ((const float4*)(embed + (size_t)idx * DD))[hl];
            }
            #pragma unroll
            for (int j = 0; j < 4; ++j) {
                if (pid[j] < len) {
                    const float pr = e[j].x * hv.x + e[j].y * hv.y
                                   + e[j].z * hv.z + e[j].w * hv.w;
                    myp[pid[j] * 33 + hl] = pr;
                }
            }
        }
    }

    // ---- phase 2: half-split partial-sum (same-wave LDS, no barrier) ----
    const int lp = l & 31;                 // pair this lane reduces
    const int kb = h * 16;                 // lanes 0-31: k 0..15; 32-63: 16..31
    float psum = 0.0f;
    #pragma unroll
    for (int k = 0; k < 16; ++k) psum += myp[lp * 33 + kb + k];
    const float dot = psum + __shfl_xor(psum, 32);

    // ---- phase 3: softplus + wave reduction ----
    float loss = 0.0f;
    if (l < 32 && lp < len) {
        // loss = softplus(code ? -dot : dot), stable BCE form
        const float z = cd_l ? -dot : dot;
        loss = fmaxf(z, 0.0f) + __logf(1.0f + __expf(-fabsf(z)));
    }
    #pragma unroll
    for (int m = 1; m <= 32; m <<= 1) loss += __shfl_xor(loss, m);

    // ---- phase 4: block pre-reduction -> one float2 per block ----
    if (l == 0) bpart[w] = make_float2(loss, (float)len);
    __syncthreads();
    if (tid == 0) {
        float L = 0.0f, C = 0.0f;
        #pragma unroll
        for (int i = 0; i < 4; ++i) { L += bpart[i].x; C += bpart[i].y; }
        partials[blockIdx.x] = make_float2(L, C);
    }
}

// Single-block reduction of the 2048 block partials (16 KB, float4 loads).
__global__ __launch_bounds__(256) void hs_finalize_kernel(
    const float2* __restrict__ partials, float* __restrict__ out)
{
    const int tid = threadIdx.x;
    const float4* p4 = (const float4*)partials;    // 1024 float4
    float ls = 0.0f, cs = 0.0f;
    #pragma unroll
    for (int k = 0; k < 4; ++k) {
        const float4 v = p4[tid + k * 256];        // {loss,cnt,loss,cnt}
        ls += v.x + v.z;
        cs += v.y + v.w;
    }
    #pragma unroll
    for (int m = 1; m <= 32; m <<= 1) {
        ls += __shfl_xor(ls, m);
        cs += __shfl_xor(cs, m);
    }
    __shared__ float s_l[4], s_c[4];
    const int wave = tid >> 6;
    if ((tid & 63) == 0) { s_l[wave] = ls; s_c[wave] = cs; }
    __syncthreads();
    if (tid == 0) {
        float L = 0.0f, C = 0.0f;
        #pragma unroll
        for (int wv = 0; wv < 4; ++wv) { L += s_l[wv]; C += s_c[wv]; }
        out[0] = L / C;
    }
}

extern "C" void kernel_launch(void* const* d_in, const int* in_sizes, int n_in,
                              void* d_out, int out_size, void* d_ws, size_t ws_size,
                              hipStream_t stream) {
    const float* hidden   = (const float*)d_in[0];  // [B, D] f32
    // d_in[1] = target (unused by the reference computation)
    const int*   path     = (const int*)d_in[2];    // [B, P]
    const int*   path_len = (const int*)d_in[3];    // [B]
    const int*   code     = (const int*)d_in[4];    // [B, P]
    const float* embed    = (const float*)d_in[5];  // [V, D] f32
    float*  out      = (float*)d_out;
    float2* partials = (float2*)d_ws;               // 2048 * 8B = 16 KB

    hs_loss_kernel<<<BB / 4, 256, 0, stream>>>(hidden, path, path_len, code,
                                               embed, partials);
    hs_finalize_kernel<<<1, 256, 0, stream>>>(partials, out);
}